// Round 5
// baseline (264.872 us; speedup 1.0000x reference)
//
#include <hip/hip_runtime.h>
#include <hip/hip_bf16.h>

typedef __attribute__((ext_vector_type(8))) short short8;
typedef __attribute__((ext_vector_type(4))) short short4v;
typedef __attribute__((ext_vector_type(4))) float floatx4;
typedef __attribute__((ext_vector_type(2))) unsigned int uint2v;
typedef unsigned short u16;

#define B_SZ 4
#define NH   16
#define SEQ  2048
#define DM   1024
#define DK   64
#define M_ROWS (B_SZ * SEQ)   // 8192

__device__ __forceinline__ u16 f2bf(float f) {
  unsigned u = __float_as_uint(f);
  u += 0x7fff + ((u >> 16) & 1);   // RNE
  return (u16)(u >> 16);
}

// packed f32x2 -> bf16x2 (RNE), single instruction
__device__ __forceinline__ unsigned cvt_pk_bf16(float lo, float hi) {
  unsigned r;
  asm("v_cvt_pk_bf16_f32 %0, %1, %2" : "=v"(r) : "v"(lo), "v"(hi));
  return r;
}

// async global->LDS: dest = wave-uniform base + lane*16B (verified constraint)
__device__ __forceinline__ void async_copy16(const u16* g, const short* lds) {
  __builtin_amdgcn_global_load_lds(
      (const __attribute__((address_space(1))) void*)g,
      (__attribute__((address_space(3))) void*)lds,
      16, 0, 0);
}

#define BAR() do { __builtin_amdgcn_s_barrier(); asm volatile("" ::: "memory"); } while (0)

// ---------------------------------------------------------------------------
// cvt4: fp32->bf16 for x (y=0) and Wq/Wk/Wv (y=1..3). grid=(1024,4).
// ---------------------------------------------------------------------------
__global__ __launch_bounds__(256)
void cvt4_kernel(const float* __restrict__ x,
                 const float* __restrict__ wq, const float* __restrict__ wk,
                 const float* __restrict__ wv,
                 u16* __restrict__ xb, u16* __restrict__ wb)
{
  const int y = blockIdx.y;
  const float* src; u16* dst; int n4;
  if (y == 0)      { src = x;  dst = xb;                 n4 = (M_ROWS * DM) / 4; }
  else if (y == 1) { src = wq; dst = wb;                 n4 = (DM * DM) / 4; }
  else if (y == 2) { src = wk; dst = wb + DM * DM;       n4 = (DM * DM) / 4; }
  else             { src = wv; dst = wb + 2 * DM * DM;   n4 = (DM * DM) / 4; }
  for (int i = blockIdx.x * 256 + threadIdx.x; i < n4; i += gridDim.x * 256) {
    floatx4 v = ((const floatx4*)src)[i];
    short4v s;
#pragma unroll
    for (int e = 0; e < 4; ++e) s[e] = (short)f2bf(v[e]);
    ((short4v*)dst)[i] = s;
  }
}

__global__ __launch_bounds__(256)
void cvt1_kernel(const float* __restrict__ in, u16* __restrict__ out, int n4)
{
  for (int i = blockIdx.x * 256 + threadIdx.x; i < n4; i += gridDim.x * 256) {
    floatx4 v = ((const floatx4*)in)[i];
    short4v s;
#pragma unroll
    for (int e = 0; e < 4; ++e) s[e] = (short)f2bf(v[e]);
    ((short4v*)out)[i] = s;
  }
}

// ---------------------------------------------------------------------------
// GEMM core, BM x 256 / BK=64 / 8 waves, templated on MIF (per-wave m-frags):
//   MIF=8 -> BM=256 (LDS 128 KiB), MIF=4 -> BM=128 (LDS 96 KiB).
// C = A(Mx1024 bf16 rm) * B^T (B Nx1024 bf16 rm), K=1024 -> 16 K-tiles,
// double-buffered.
//
// ROUND-5 RESTRUCTURE: 2-barrier counted-wait K-tile (replaces the 8-barrier
// lockstep, which at 1 block/CU serialized LDS-phase and MFMA-phase: measured
// ~7000 cyc/K-tile vs ~2500 floor).  Per tile t (buf c):
//   issue ALL 24 ds_read_b128 (B-lo, A-lo, B-hi, A-hi) into regs
//   q1 (m-lo x n-lo), q2 (m-lo x n-hi), q3 (m-hi x n-hi)   [compiler emits
//     counted lgkmcnt(N) before each quadrant -- LDS stream || MFMA stream]
//   BAR()         // ledger hazard (a): q1..q3's waits cover all 24 reads in
//                 // program order => every wave's reads of buf[c] retired
//   stage(t+2) -> buf[c];  vmcnt(L)   // (L=loads/thread/K-tile: t+1 landed)
//   q4 (m-hi x n-lo)                  // pure reg ops, overlaps staging issue
//   BAR()         // ledger hazard (b): ALL waves' t+1 loads landed
// LDS swizzle (T2) unchanged: LDS[row][cu] = global[row][cu^(row&7)],
// staged pre-swizzled (linear global_load_lds dest), read with same XOR.
// ---------------------------------------------------------------------------
__device__ __forceinline__ void stage_tile_half(
    const u16* __restrict__ src,   // element (row0_of_half, k0)
    short* dst,                    // LDS base of this 128x64 half
    int wid, int lane)
{
#pragma unroll
  for (int j = 0; j < 2; ++j) {
    const int oct = wid + j * 8;                 // 0..15 (8 rows each)
    const int row = oct * 8 + (lane >> 3);
    const int cu  = (lane & 7) ^ (lane >> 3);    // pre-swizzled col-unit (16B)
    async_copy16(src + (size_t)row * DM + cu * 8, dst + oct * 512);
  }
}

template<int MIF>
__device__ __forceinline__ void gemm256_core(
    const u16* __restrict__ A, const u16* __restrict__ B,
    int m0, int n0, floatx4 (&acc)[MIF][4])
{
  constexpr int ASH = MIF * 32 * 64;       // shorts per A buffer (BM x 64)
  constexpr int AH  = MIF / 4;             // A stage-halves (128-row units)
  constexpr int L   = 2 * (AH + 2);        // gloads/thread per K-tile (8 or 6)

  __shared__ short smem[2 * (ASH + 16384)];

  const int tid  = threadIdx.x;
  const int wid  = tid >> 6;
  const int lane = tid & 63;
  const int wm   = wid >> 2, wn = wid & 3;       // wave grid 2(M) x 4(N)
  const int quad = lane >> 4, l16 = lane & 15;
  const int swz  = l16 & 7;                      // row&7 == l16&7 for all frags

  short* sA_[2] = { smem,       smem + ASH + 16384 };
  short* sB_[2] = { smem + ASH, smem + 2 * ASH + 16384 };

#pragma unroll
  for (int mi = 0; mi < MIF; ++mi)
#pragma unroll
    for (int ni = 0; ni < 4; ++ni)
      acc[mi][ni] = floatx4{0.f, 0.f, 0.f, 0.f};

  const u16* Abase = A + (size_t)m0 * DM;
  const u16* Bbase = B + (size_t)n0 * DM;

#define STAGE_TILE(kof, c) do {                                              \
    _Pragma("unroll")                                                        \
    for (int u = 0; u < AH; ++u)                                             \
      stage_tile_half(Abase + (size_t)(u * 128) * DM + (kof),                \
                      sA_[c] + u * 8192, wid, lane);                         \
    stage_tile_half(Bbase + (kof),                    sB_[c],        wid, lane); \
    stage_tile_half(Bbase + (size_t)128 * DM + (kof), sB_[c] + 8192, wid, lane); \
  } while (0)

#define VMCNT_L() do {                                                       \
    if constexpr (L == 8) asm volatile("s_waitcnt vmcnt(8)" ::: "memory");   \
    else                  asm volatile("s_waitcnt vmcnt(6)" ::: "memory");   \
  } while (0)

  // ---- prologue: stage tiles 0 (buf0) and 1 (buf1) ----
  STAGE_TILE(0, 0);
  STAGE_TILE(64, 1);
  VMCNT_L();                                     // tile0 landed
  BAR();

  short8 af[MIF][2], bf[4][2];

  for (int i = 0; i < 8; ++i) {                  // tiles 2i, 2i+1
    const bool nl = (i < 7);                     // stage tiles 2i+2 / 2i+3
#pragma unroll
    for (int half = 0; half < 2; ++half) {
      short* cA = sA_[half];
      short* cB = sB_[half];
      const int kof_n = (2 * i + 2 + half) * 64; // staging k-offset (if nl)

      // ---- issue ALL K-tile ds_reads (order: B-lo, A-lo, B-hi, A-hi) ----
#pragma unroll
      for (int nt = 0; nt < 2; ++nt)
#pragma unroll
        for (int kk = 0; kk < 2; ++kk)
          bf[nt][kk] = *(const short8*)(cB + (wn * 64 + nt * 16 + l16) * 64
                                           + (((kk * 4 + quad) ^ swz) << 3));
#pragma unroll
      for (int mi = 0; mi < MIF / 2; ++mi)
#pragma unroll
        for (int kk = 0; kk < 2; ++kk)
          af[mi][kk] = *(const short8*)(cA + (wm * (MIF * 16) + mi * 16 + l16) * 64
                                           + (((kk * 4 + quad) ^ swz) << 3));
#pragma unroll
      for (int nt = 2; nt < 4; ++nt)
#pragma unroll
        for (int kk = 0; kk < 2; ++kk)
          bf[nt][kk] = *(const short8*)(cB + (wn * 64 + nt * 16 + l16) * 64
                                           + (((kk * 4 + quad) ^ swz) << 3));
#pragma unroll
      for (int mi = MIF / 2; mi < MIF; ++mi)
#pragma unroll
        for (int kk = 0; kk < 2; ++kk)
          af[mi][kk] = *(const short8*)(cA + (wm * (MIF * 16) + mi * 16 + l16) * 64
                                           + (((kk * 4 + quad) ^ swz) << 3));

      // ---- q1 (m-lo x n-lo), q2 (m-lo x n-hi), q3 (m-hi x n-hi) ----
      __builtin_amdgcn_s_setprio(1);
#pragma unroll
      for (int mi = 0; mi < MIF / 2; ++mi)
#pragma unroll
        for (int nt = 0; nt < 2; ++nt)
#pragma unroll
          for (int kk = 0; kk < 2; ++kk)
            acc[mi][nt] = __builtin_amdgcn_mfma_f32_16x16x32_bf16(
                af[mi][kk], bf[nt][kk], acc[mi][nt], 0, 0, 0);
#pragma unroll
      for (int mi = 0; mi < MIF / 2; ++mi)
#pragma unroll
        for (int nt = 2; nt < 4; ++nt)
#pragma unroll
          for (int kk = 0; kk < 2; ++kk)
            acc[mi][nt] = __builtin_amdgcn_mfma_f32_16x16x32_bf16(
                af[mi][kk], bf[nt][kk], acc[mi][nt], 0, 0, 0);
#pragma unroll
      for (int mi = MIF / 2; mi < MIF; ++mi)
#pragma unroll
        for (int nt = 2; nt < 4; ++nt)
#pragma unroll
          for (int kk = 0; kk < 2; ++kk)
            acc[mi][nt] = __builtin_amdgcn_mfma_f32_16x16x32_bf16(
                af[mi][kk], bf[nt][kk], acc[mi][nt], 0, 0, 0);
      __builtin_amdgcn_s_setprio(0);

      BAR();   // hazard (a): all waves' reads of this buffer retired

      if (nl) {
        STAGE_TILE(kof_n, half);
        VMCNT_L();                               // tile t+1 landed (mine)
      } else {
        asm volatile("s_waitcnt vmcnt(0)" ::: "memory");  // drain final tiles
      }

      // ---- q4 (m-hi x n-lo): pure reg ops, overlaps staging issue ----
      __builtin_amdgcn_s_setprio(1);
#pragma unroll
      for (int mi = MIF / 2; mi < MIF; ++mi)
#pragma unroll
        for (int nt = 0; nt < 2; ++nt)
#pragma unroll
          for (int kk = 0; kk < 2; ++kk)
            acc[mi][nt] = __builtin_amdgcn_mfma_f32_16x16x32_bf16(
                af[mi][kk], bf[nt][kk], acc[mi][nt], 0, 0, 0);
      __builtin_amdgcn_s_setprio(0);

      BAR();   // hazard (b): ALL waves' t+1 loads landed
    }
  }
#undef STAGE_TILE
#undef VMCNT_L
}

// ---------------------------------------------------------------------------
// Fused QKV projection, 256^2 tiles. grid = (384): [0,128) Q, [128,256) K,
// [256,384) V^T (operands swapped: C[e][s] = sum_d Wv[e][d] x[s][d], so the
// (b,h,d,s) store is contiguous in s -- no 4KB-stride scatter).
// ---------------------------------------------------------------------------
__global__ __launch_bounds__(512, 2)
void qkv256_kernel(const u16* __restrict__ xb, const u16* __restrict__ wb,
                   const float* __restrict__ bq, const float* __restrict__ bk,
                   const float* __restrict__ bv,
                   u16* __restrict__ Qo, u16* __restrict__ Ko, u16* __restrict__ Vto)
{
  const int bx = blockIdx.x;
  const int wg = (bx & 7) * 48 + (bx >> 3);      // bijective XCD swizzle (384%8==0)
  const int mat = wg >> 7;
  const int r   = wg & 127;

  int m0, n0;
  const u16 *A, *Bm;
  if (mat < 2) { m0 = (r >> 2) * 256; n0 = (r & 3) * 256; A = xb; Bm = wb + (size_t)mat * DM * DM; }
  else         { m0 = (r & 3) * 256;  n0 = (r >> 2) * 256; A = wb + (size_t)2 * DM * DM; Bm = xb; }

  floatx4 acc[8][4];
  gemm256_core<8>(A, Bm, m0, n0, acc);

  const int tid = threadIdx.x;
  const int wid = tid >> 6, lane = tid & 63;
  const int wm = wid >> 2, wn = wid & 3;
  const int quad = lane >> 4, l16 = lane & 15;

  if (mat < 2) {
    u16* dst = (mat == 0) ? Qo : Ko;
    const float* bias = (mat == 0) ? bq : bk;
#pragma unroll
    for (int ni = 0; ni < 4; ++ni) {
      const int n = n0 + wn * 64 + ni * 16 + l16;
      const float bb = bias[n];
      const int h = n >> 6, d = n & 63;
#pragma unroll
      for (int mi = 0; mi < 8; ++mi)
#pragma unroll
        for (int rr = 0; rr < 4; ++rr) {
          const int m = m0 + wm * 128 + mi * 16 + quad * 4 + rr;
          const int b = m >> 11, s = m & 2047;
          dst[((size_t)(b * NH + h) * SEQ + s) * DK + d] = f2bf(acc[mi][ni][rr] + bb);
        }
    }
  } else {
#pragma unroll
    for (int mi = 0; mi < 8; ++mi)
#pragma unroll
      for (int rr = 0; rr < 4; ++rr) {
        const int m = m0 + wm * 128 + mi * 16 + quad * 4 + rr;   // e in [0,1024)
        const float bb = bv[m];
        const int h = m >> 6, d = m & 63;
#pragma unroll
        for (int ni = 0; ni < 4; ++ni) {
          const int n = n0 + wn * 64 + ni * 16 + l16;            // (b,s) in [0,8192)
          const int b = n >> 11, s = n & 2047;
          Vto[((size_t)(b * NH + h) * DK + d) * SEQ + s] = f2bf(acc[mi][ni][rr] + bb);
        }
      }
  }
}

// ---------------------------------------------------------------------------
// Flash attention, causal, exp2-domain, no-rescale online softmax.
// grid = (64 bh, 16 qt-reversed). Block = 128 q-rows, 4 waves x 32 rows.
// Swapped QK^T (lane-local P) + cvt_pk + b64 P-stores (round 4, passed).
// ---------------------------------------------------------------------------
#define AT_STR 72
__global__ __launch_bounds__(256, 2)
void attn_kernel(const u16* __restrict__ Q, const u16* __restrict__ Kx,
                 const u16* __restrict__ Vt, u16* __restrict__ O)
{
  __shared__ short Ks[64 * 64];
  __shared__ short Vs[64 * 64];
  __shared__ __align__(16) short Ps[4 * 16 * AT_STR];   // 16 rows per wave

  const int bh  = blockIdx.x;
  const int qtb = 15 - (int)blockIdx.y;
  const int q0  = qtb * 128;
  const int tid = threadIdx.x;
  const int w = tid >> 6, lane = tid & 63;
  const int quad = lane >> 4, l16 = lane & 15;
  const int r8 = lane >> 3, c8 = lane & 7;

  const u16* Qh = Q  + (size_t)bh * SEQ * DK;
  const u16* Kh = Kx + (size_t)bh * SEQ * DK;
  const u16* Vh = Vt + (size_t)bh * DK * SEQ;

  short8 qf[2][2];
#pragma unroll
  for (int qp = 0; qp < 2; ++qp) {
    const int qrow = q0 + w * 32 + qp * 16 + l16;
#pragma unroll
    for (int h = 0; h < 2; ++h)
      qf[qp][h] = *(const short8*)(Qh + (size_t)qrow * DK + h * 32 + quad * 8);
  }

  short8 vone;
#pragma unroll
  for (int j = 0; j < 8; ++j) vone[j] = (l16 == 0) ? (short)0x3F80 : (short)0;

  floatx4 o[2][4], ls[2];
#pragma unroll
  for (int qp = 0; qp < 2; ++qp) {
    ls[qp] = floatx4{0.f, 0.f, 0.f, 0.f};
#pragma unroll
    for (int dt = 0; dt < 4; ++dt) o[qp][dt] = floatx4{0.f, 0.f, 0.f, 0.f};
  }

  const float SC2 = 0.18033688011f;   // (1/8) * log2(e)
  const int ktmax = 2 * qtb + 2;
  short* Pw = Ps + w * 16 * AT_STR;   // this wave's 16-row P buffer

  for (int kt = 0; kt < ktmax; ++kt) {
    const int k0 = kt * 64;
    __syncthreads();
#pragma unroll
    for (int c = 0; c < 2; ++c) {
      const int row8 = w * 16 + c * 8;   // wave-uniform
      const int sw   = (c8 ^ r8) * 8;
      async_copy16(Kh + (size_t)(k0 + row8 + r8) * DK + sw, Ks + row8 * 64);
      async_copy16(Vh + (size_t)(row8 + r8) * SEQ + k0 + sw, Vs + row8 * 64);
    }
    __syncthreads();

    short8 kf[4][2], vf[4][2];
#pragma unroll
    for (int nt = 0; nt < 4; ++nt)
#pragma unroll
      for (int h = 0; h < 2; ++h) {
        kf[nt][h] = *(const short8*)(Ks + (nt * 16 + l16) * 64 + (((h * 4 + quad) ^ (l16 & 7)) * 8));
        vf[nt][h] = *(const short8*)(Vs + (nt * 16 + l16) * 64 + (((h * 4 + quad) ^ (l16 & 7)) * 8));
      }

#pragma unroll
    for (int qp = 0; qp < 2; ++qp) {
      const int frag0 = q0 + w * 32 + qp * 16;
      if (k0 <= frag0 + 15) {
        // swapped QK^T: D[key][query] -> lane holds q-row = l16,
        // keys k0 + nt*16 + quad*4 + r  (r = reg)
        floatx4 sc[4];
#pragma unroll
        for (int nt = 0; nt < 4; ++nt) {
          floatx4 z = floatx4{0.f, 0.f, 0.f, 0.f};
          z = __builtin_amdgcn_mfma_f32_16x16x32_bf16(kf[nt][0], qf[qp][0], z, 0, 0, 0);
          z = __builtin_amdgcn_mfma_f32_16x16x32_bf16(kf[nt][1], qf[qp][1], z, 0, 0, 0);
          sc[nt] = z;
        }
        const bool diag = (k0 + 63 > frag0);
        const int qrow = frag0 + l16;
#pragma unroll
        for (int nt = 0; nt < 4; ++nt)
#pragma unroll
          for (int r = 0; r < 4; ++r) {
            float s = sc[nt][r] * SC2;
            if (diag) {
              const int col = k0 + nt * 16 + quad * 4 + r;
              if (col > qrow) s = -1e30f;
            }
            sc[nt][r] = __builtin_amdgcn_exp2f(s);
          }
        // pack pairs + b64 stores: row = l16 (own q-row), cols nt*16+quad*4..+3
#pragma unroll
        for (int nt = 0; nt < 4; ++nt) {
          uint2v wv2;
          wv2[0] = cvt_pk_bf16(sc[nt][0], sc[nt][1]);
          wv2[1] = cvt_pk_bf16(sc[nt][2], sc[nt][3]);
          *(short4v*)(Pw + l16 * AT_STR + nt * 16 + quad * 4) =
              __builtin_bit_cast(short4v, wv2);
        }
        asm volatile("" ::: "memory");   // keep pf reads after P writes
        short8 pf[2];
#pragma unroll
        for (int h = 0; h < 2; ++h)
          pf[h] = *(const short8*)(Pw + l16 * AT_STR + h * 32 + quad * 8);
#pragma unroll
        for (int dt = 0; dt < 4; ++dt) {
          o[qp][dt] = __builtin_amdgcn_mfma_f32_16x16x32_bf16(pf[0], vf[dt][0], o[qp][dt], 0, 0, 0);
          o[qp][dt] = __builtin_amdgcn_mfma_f32_16x16x32_bf16(pf[1], vf[dt][1], o[qp][dt], 0, 0, 0);
        }
        ls[qp] = __builtin_amdgcn_mfma_f32_16x16x32_bf16(pf[0], vone, ls[qp], 0, 0, 0);
        ls[qp] = __builtin_amdgcn_mfma_f32_16x16x32_bf16(pf[1], vone, ls[qp], 0, 0, 0);
      }
    }
  }

  const int b = bh >> 4, h = bh & 15;
#pragma unroll
  for (int qp = 0; qp < 2; ++qp) {
    const int frag0 = q0 + w * 32 + qp * 16;
#pragma unroll
    for (int r = 0; r < 4; ++r) {
      const float lv  = __shfl(ls[qp][r], lane & 48);
      const float inv = 1.0f / fmaxf(lv, 1e-20f);
      const int row   = frag0 + quad * 4 + r;
      const size_t base = ((size_t)b * SEQ + row) * DM + h * DK;
#pragma unroll
      for (int dt = 0; dt < 4; ++dt)
        O[base + dt * 16 + l16] = f2bf(o[qp][dt][r] * inv);
    }
  }
}

// ---------------------------------------------------------------------------
// Output projection: out = O'(bf16) @ Wo_b^T + bo, fp32 out.
// 128x256 tiles (MIF=4, LDS 96 KiB) -> grid = 256 = exactly one full round
// (the old 256^2 grid of 128 left half the machine idle).
// ---------------------------------------------------------------------------
__global__ __launch_bounds__(512, 2)
void oproj256_kernel(const u16* __restrict__ A, const u16* __restrict__ Wob,
                     const float* __restrict__ bo, float* __restrict__ out)
{
  const int bx = blockIdx.x;
  const int wg = (bx & 7) * 32 + (bx >> 3);      // 256 % 8 == 0
  const int m0 = (wg >> 2) * 128, n0 = (wg & 3) * 256;

  floatx4 acc[4][4];
  gemm256_core<4>(A, Wob, m0, n0, acc);

  const int tid = threadIdx.x;
  const int wid = tid >> 6, lane = tid & 63;
  const int wm = wid >> 2, wn = wid & 3;
  const int quad = lane >> 4, l16 = lane & 15;

#pragma unroll
  for (int ni = 0; ni < 4; ++ni) {
    const int n = n0 + wn * 64 + ni * 16 + l16;
    const float bb = bo[n];
#pragma unroll
    for (int mi = 0; mi < 4; ++mi)
#pragma unroll
      for (int rr = 0; rr < 4; ++rr) {
        const int m = m0 + wm * 64 + mi * 16 + quad * 4 + rr;
        out[(size_t)m * DM + n] = acc[mi][ni][rr] + bb;
      }
  }
}

extern "C" void kernel_launch(void* const* d_in, const int* in_sizes, int n_in,
                              void* d_out, int out_size, void* d_ws, size_t ws_size,
                              hipStream_t stream)
{
  const float* x  = (const float*)d_in[0];
  const float* Wq = (const float*)d_in[1];
  const float* bq = (const float*)d_in[2];
  const float* Wk = (const float*)d_in[3];
  const float* bk = (const float*)d_in[4];
  const float* Wv = (const float*)d_in[5];
  const float* bv = (const float*)d_in[6];
  const float* Wo = (const float*)d_in[7];
  const float* bo = (const float*)d_in[8];
  float* out = (float*)d_out;

  // ws (64 MiB): Q, K, Vt, O'  (qws doubles as Wo_b after attn)
  u16* qws  = (u16*)d_ws;                       // (b,h,s,d)  bf16, 16 MiB
  u16* kws  = qws  + (size_t)M_ROWS * DM;       // (b,h,s,d)  bf16, 16 MiB
  u16* vtws = kws  + (size_t)M_ROWS * DM;       // (b,h,d,s)  bf16, 16 MiB
  u16* ows  = vtws + (size_t)M_ROWS * DM;       // O' (b,s,h*d) bf16, 16 MiB

  // d_out doubles as scratch until oproj overwrites all of it:
  //   [0, 16 MiB)  : x bf16
  //   [16, 22 MiB) : Wq/Wk/Wv bf16 packed [3][DM][DM]
  u16* xb = (u16*)d_out;
  u16* wb = xb + (size_t)M_ROWS * DM;
  u16* wo_b = qws;                              // qws dead after attn

  cvt4_kernel  <<<dim3(1024, 4), 256, 0, stream>>>(x, Wq, Wk, Wv, xb, wb);
  qkv256_kernel<<<dim3(384), 512, 0, stream>>>(xb, wb, bq, bk, bv, qws, kws, vtws);
  attn_kernel  <<<dim3(64, 16), 256, 0, stream>>>(qws, kws, vtws, ows);
  cvt1_kernel  <<<dim3(1024), 256, 0, stream>>>(Wo, wo_b, (DM * DM) / 4);
  oproj256_kernel<<<dim3(256), 512, 0, stream>>>(ows, wo_b, bo, out);
}

// Round 7
// 259.866 us; speedup vs baseline: 1.0193x; 1.0193x over previous
//
#include <hip/hip_runtime.h>
#include <hip/hip_bf16.h>

typedef __attribute__((ext_vector_type(8))) short short8;
typedef __attribute__((ext_vector_type(4))) short short4v;
typedef __attribute__((ext_vector_type(4))) float floatx4;
typedef __attribute__((ext_vector_type(2))) unsigned int uint2v;
typedef unsigned short u16;

#define B_SZ 4
#define NH   16
#define SEQ  2048
#define DM   1024
#define DK   64
#define M_ROWS (B_SZ * SEQ)   // 8192

__device__ __forceinline__ u16 f2bf(float f) {
  unsigned u = __float_as_uint(f);
  u += 0x7fff + ((u >> 16) & 1);   // RNE
  return (u16)(u >> 16);
}

// packed f32x2 -> bf16x2 (RNE), single instruction
__device__ __forceinline__ unsigned cvt_pk_bf16(float lo, float hi) {
  unsigned r;
  asm("v_cvt_pk_bf16_f32 %0, %1, %2" : "=v"(r) : "v"(lo), "v"(hi));
  return r;
}

// async global->LDS: dest = wave-uniform base + lane*16B (verified constraint)
__device__ __forceinline__ void async_copy16(const u16* g, const short* lds) {
  __builtin_amdgcn_global_load_lds(
      (const __attribute__((address_space(1))) void*)g,
      (__attribute__((address_space(3))) void*)lds,
      16, 0, 0);
}

#define BAR() do { __builtin_amdgcn_s_barrier(); asm volatile("" ::: "memory"); } while (0)

// ---------------------------------------------------------------------------
// cvt4: fp32->bf16 for x (y=0) and Wq/Wk/Wv (y=1..3). grid=(1024,4).
// ---------------------------------------------------------------------------
__global__ __launch_bounds__(256)
void cvt4_kernel(const float* __restrict__ x,
                 const float* __restrict__ wq, const float* __restrict__ wk,
                 const float* __restrict__ wv,
                 u16* __restrict__ xb, u16* __restrict__ wb)
{
  const int y = blockIdx.y;
  const float* src; u16* dst; int n4;
  if (y == 0)      { src = x;  dst = xb;                 n4 = (M_ROWS * DM) / 4; }
  else if (y == 1) { src = wq; dst = wb;                 n4 = (DM * DM) / 4; }
  else if (y == 2) { src = wk; dst = wb + DM * DM;       n4 = (DM * DM) / 4; }
  else             { src = wv; dst = wb + 2 * DM * DM;   n4 = (DM * DM) / 4; }
  for (int i = blockIdx.x * 256 + threadIdx.x; i < n4; i += gridDim.x * 256) {
    floatx4 v = ((const floatx4*)src)[i];
    short4v s;
#pragma unroll
    for (int e = 0; e < 4; ++e) s[e] = (short)f2bf(v[e]);
    ((short4v*)dst)[i] = s;
  }
}

__global__ __launch_bounds__(256)
void cvt1_kernel(const float* __restrict__ in, u16* __restrict__ out, int n4)
{
  for (int i = blockIdx.x * 256 + threadIdx.x; i < n4; i += gridDim.x * 256) {
    floatx4 v = ((const floatx4*)in)[i];
    short4v s;
#pragma unroll
    for (int e = 0; e < 4; ++e) s[e] = (short)f2bf(v[e]);
    ((short4v*)out)[i] = s;
  }
}

// ---------------------------------------------------------------------------
// GEMM core, BM x 256 / BK=32 / 8 waves, templated on MIF (per-wave m-frags):
//   MIF=8 -> BM=256, LDS 64 KiB  -> 2 blocks/CU co-resident
//   MIF=4 -> BM=128, LDS 48 KiB
// C = A(Mx1024 bf16 rm) * B^T (B Nx1024 bf16 rm), K=1024 -> 32 K-tiles,
// double-buffered (buf parity = tile parity).
//
// BK 64->32 rationale: one 16x16x32 MFMA is ~19.4 cyc/SIMD (2075 TF ubench),
// so a BK=64 K-tile is MFMA-floor ~2480 cyc/SIMD; we measured ~6300 ->
// pipes idle >55% because 128 KiB LDS forced 1 block/CU (2 waves/SIMD,
// lockstep barriers, nothing fills the stalls).  Halving BK halves LDS ->
// 2 blocks/CU: co-resident block fills barrier windows (m114 mechanism),
// grid 384 fully resident (no 2nd round).
//
// Swizzle (64B rows): LDS[r][u] = G[r][u ^ (r&3) ^ ((r>>2)&3)], u = 16B unit.
// Read unit = quad ^ (l16&3) ^ ((l16>>2)&3)  (wm/wn/mi/nt are x16 -> drop).
// 64 lanes -> uniform 8 per 16B slot mod 128B = conflict-free class (same as
// the measured-0-conflict BK=64 layout).  Staged via pre-swizzled global
// source, linear global_load_lds dest (both-sides-or-neither rule).
//
// 2-barrier ledger per tile t (buf c): issue all 12 (MIF=8) ds_reads; MFMA
// q1(m-lo,n-lo) q2(m-lo,n-hi) q3(m-hi,n-hi) [auto counted lgkm waits cover
// all reads]; BAR(a); stage(t+2)->buf c; vmcnt(L) [t+1 landed, L=AH+2];
// q4(m-hi,n-lo) from regs; BAR(b).
// ---------------------------------------------------------------------------
__device__ __forceinline__ void stage_half32(
    const u16* __restrict__ src,   // element (row0_of_half, k0)
    short* dst,                    // LDS base of this 128x32 half
    int wid, int lane)
{
  const int row = wid * 16 + (lane >> 2);                          // 0..127
  const int cu  = (lane & 3) ^ ((lane >> 2) & 3) ^ ((lane >> 4) & 3);
  async_copy16(src + (size_t)row * DM + cu * 8, dst + wid * 512);
}

template<int MIF>
__device__ __forceinline__ void gemm256_core(
    const u16* __restrict__ A, const u16* __restrict__ B,
    int m0, int n0, floatx4 (&acc)[MIF][4])
{
  constexpr int ASH = MIF * 32 * 32;       // shorts per A buffer (BM x 32)
  constexpr int AH  = MIF / 4;             // A halves (128-row units)
  constexpr int L   = AH + 2;              // gloads/wave per K-tile (4 or 3)

  __shared__ short smem[2 * (ASH + 8192)];

  const int tid  = threadIdx.x;
  const int wid  = tid >> 6;
  const int lane = tid & 63;
  const int wm   = wid >> 2, wn = wid & 3;       // wave grid 2(M) x 4(N)
  const int quad = lane >> 4, l16 = lane & 15;
  const int rswz = (l16 & 3) ^ ((l16 >> 2) & 3);

  short* sA_[2] = { smem,       smem + ASH + 8192 };
  short* sB_[2] = { smem + ASH, smem + 2 * ASH + 8192 };

#pragma unroll
  for (int mi = 0; mi < MIF; ++mi)
#pragma unroll
    for (int ni = 0; ni < 4; ++ni)
      acc[mi][ni] = floatx4{0.f, 0.f, 0.f, 0.f};

  const u16* Abase = A + (size_t)m0 * DM;
  const u16* Bbase = B + (size_t)n0 * DM;

#define STAGE_TILE(kof, c) do {                                              \
    _Pragma("unroll")                                                        \
    for (int u = 0; u < AH; ++u)                                             \
      stage_half32(Abase + (size_t)(u * 128) * DM + (kof),                   \
                   sA_[c] + u * 4096, wid, lane);                            \
    stage_half32(Bbase + (kof),                    sB_[c],        wid, lane); \
    stage_half32(Bbase + (size_t)128 * DM + (kof), sB_[c] + 4096, wid, lane); \
  } while (0)

#define VMCNT_L() do {                                                       \
    if constexpr (L == 4) asm volatile("s_waitcnt vmcnt(4)" ::: "memory");   \
    else                  asm volatile("s_waitcnt vmcnt(3)" ::: "memory");   \
  } while (0)

  // ---- prologue: stage tiles 0 (buf0) and 1 (buf1) ----
  STAGE_TILE(0, 0);
  STAGE_TILE(32, 1);
  VMCNT_L();                                     // tile0 landed
  BAR();

  short8 af[MIF], bf[4];

  for (int i = 0; i < 16; ++i) {                 // tiles 2i, 2i+1
    const bool nl = (i < 15);                    // stage tiles 2i+2 / 2i+3
#pragma unroll
    for (int half = 0; half < 2; ++half) {
      short* cA = sA_[half];
      short* cB = sB_[half];
      const int kof_n = (2 * i + 2 + half) * 32; // staging k-offset (if nl)

      // ---- issue ALL K-tile ds_reads (order: B-lo, A-lo, B-hi, A-hi) ----
#pragma unroll
      for (int nt = 0; nt < 2; ++nt)
        bf[nt] = *(const short8*)(cB + (wn * 64 + nt * 16 + l16) * 32
                                     + (((quad) ^ rswz) << 3));
#pragma unroll
      for (int mi = 0; mi < MIF / 2; ++mi)
        af[mi] = *(const short8*)(cA + (wm * (MIF * 16) + mi * 16 + l16) * 32
                                     + (((quad) ^ rswz) << 3));
#pragma unroll
      for (int nt = 2; nt < 4; ++nt)
        bf[nt] = *(const short8*)(cB + (wn * 64 + nt * 16 + l16) * 32
                                     + (((quad) ^ rswz) << 3));
#pragma unroll
      for (int mi = MIF / 2; mi < MIF; ++mi)
        af[mi] = *(const short8*)(cA + (wm * (MIF * 16) + mi * 16 + l16) * 32
                                     + (((quad) ^ rswz) << 3));

      // ---- q1 (m-lo x n-lo), q2 (m-lo x n-hi), q3 (m-hi x n-hi) ----
      __builtin_amdgcn_s_setprio(1);
#pragma unroll
      for (int mi = 0; mi < MIF / 2; ++mi)
#pragma unroll
        for (int nt = 0; nt < 2; ++nt)
          acc[mi][nt] = __builtin_amdgcn_mfma_f32_16x16x32_bf16(
              af[mi], bf[nt], acc[mi][nt], 0, 0, 0);
#pragma unroll
      for (int mi = 0; mi < MIF / 2; ++mi)
#pragma unroll
        for (int nt = 2; nt < 4; ++nt)
          acc[mi][nt] = __builtin_amdgcn_mfma_f32_16x16x32_bf16(
              af[mi], bf[nt], acc[mi][nt], 0, 0, 0);
#pragma unroll
      for (int mi = MIF / 2; mi < MIF; ++mi)
#pragma unroll
        for (int nt = 2; nt < 4; ++nt)
          acc[mi][nt] = __builtin_amdgcn_mfma_f32_16x16x32_bf16(
              af[mi], bf[nt], acc[mi][nt], 0, 0, 0);
      __builtin_amdgcn_s_setprio(0);

      BAR();   // hazard (a): all waves' reads of this buffer retired

      if (nl) {
        STAGE_TILE(kof_n, half);
        VMCNT_L();                               // tile t+1 landed (mine)
      } else {
        asm volatile("s_waitcnt vmcnt(0)" ::: "memory");  // drain final tiles
      }

      // ---- q4 (m-hi x n-lo): pure reg ops, overlaps staging issue ----
      __builtin_amdgcn_s_setprio(1);
#pragma unroll
      for (int mi = MIF / 2; mi < MIF; ++mi)
#pragma unroll
        for (int nt = 0; nt < 2; ++nt)
          acc[mi][nt] = __builtin_amdgcn_mfma_f32_16x16x32_bf16(
              af[mi], bf[nt], acc[mi][nt], 0, 0, 0);
      __builtin_amdgcn_s_setprio(0);

      BAR();   // hazard (b): ALL waves' t+1 loads landed
    }
  }
#undef STAGE_TILE
#undef VMCNT_L
}

// ---------------------------------------------------------------------------
// Fused QKV projection, 256^2 tiles. grid = (384): [0,128) Q, [128,256) K,
// [256,384) V^T (operands swapped: C[e][s] = sum_d Wv[e][d] x[s][d], so the
// (b,h,d,s) store is contiguous in s -- no 4KB-stride scatter).
// ---------------------------------------------------------------------------
__global__ __launch_bounds__(512, 2)
void qkv256_kernel(const u16* __restrict__ xb, const u16* __restrict__ wb,
                   const float* __restrict__ bq, const float* __restrict__ bk,
                   const float* __restrict__ bv,
                   u16* __restrict__ Qo, u16* __restrict__ Ko, u16* __restrict__ Vto)
{
  const int bx = blockIdx.x;
  const int wg = (bx & 7) * 48 + (bx >> 3);      // bijective XCD swizzle (384%8==0)
  const int mat = wg >> 7;
  const int r   = wg & 127;

  int m0, n0;
  const u16 *A, *Bm;
  if (mat < 2) { m0 = (r >> 2) * 256; n0 = (r & 3) * 256; A = xb; Bm = wb + (size_t)mat * DM * DM; }
  else         { m0 = (r & 3) * 256;  n0 = (r >> 2) * 256; A = wb + (size_t)2 * DM * DM; Bm = xb; }

  floatx4 acc[8][4];
  gemm256_core<8>(A, Bm, m0, n0, acc);

  const int tid = threadIdx.x;
  const int wid = tid >> 6, lane = tid & 63;
  const int wm = wid >> 2, wn = wid & 3;
  const int quad = lane >> 4, l16 = lane & 15;

  if (mat < 2) {
    u16* dst = (mat == 0) ? Qo : Ko;
    const float* bias = (mat == 0) ? bq : bk;
#pragma unroll
    for (int ni = 0; ni < 4; ++ni) {
      const int n = n0 + wn * 64 + ni * 16 + l16;
      const float bb = bias[n];
      const int h = n >> 6, d = n & 63;
#pragma unroll
      for (int mi = 0; mi < 8; ++mi)
#pragma unroll
        for (int rr = 0; rr < 4; ++rr) {
          const int m = m0 + wm * 128 + mi * 16 + quad * 4 + rr;
          const int b = m >> 11, s = m & 2047;
          dst[((size_t)(b * NH + h) * SEQ + s) * DK + d] = f2bf(acc[mi][ni][rr] + bb);
        }
    }
  } else {
#pragma unroll
    for (int mi = 0; mi < 8; ++mi)
#pragma unroll
      for (int rr = 0; rr < 4; ++rr) {
        const int m = m0 + wm * 128 + mi * 16 + quad * 4 + rr;   // e in [0,1024)
        const float bb = bv[m];
        const int h = m >> 6, d = m & 63;
#pragma unroll
        for (int ni = 0; ni < 4; ++ni) {
          const int n = n0 + wn * 64 + ni * 16 + l16;            // (b,s) in [0,8192)
          const int b = n >> 11, s = n & 2047;
          Vto[((size_t)(b * NH + h) * DK + d) * SEQ + s] = f2bf(acc[mi][ni][rr] + bb);
        }
      }
  }
}

// ---------------------------------------------------------------------------
// Flash attention, causal, exp2-domain, no-rescale online softmax.
// grid = (64 bh, 16 qt-reversed). Block = 128 q-rows, 4 waves x 32 rows.
// Swapped QK^T (lane-local P) + cvt_pk + b64 P-stores (round 4, passed).
// ---------------------------------------------------------------------------
#define AT_STR 72
__global__ __launch_bounds__(256, 2)
void attn_kernel(const u16* __restrict__ Q, const u16* __restrict__ Kx,
                 const u16* __restrict__ Vt, u16* __restrict__ O)
{
  __shared__ short Ks[64 * 64];
  __shared__ short Vs[64 * 64];
  __shared__ __align__(16) short Ps[4 * 16 * AT_STR];   // 16 rows per wave

  const int bh  = blockIdx.x;
  const int qtb = 15 - (int)blockIdx.y;
  const int q0  = qtb * 128;
  const int tid = threadIdx.x;
  const int w = tid >> 6, lane = tid & 63;
  const int quad = lane >> 4, l16 = lane & 15;
  const int r8 = lane >> 3, c8 = lane & 7;

  const u16* Qh = Q  + (size_t)bh * SEQ * DK;
  const u16* Kh = Kx + (size_t)bh * SEQ * DK;
  const u16* Vh = Vt + (size_t)bh * DK * SEQ;

  short8 qf[2][2];
#pragma unroll
  for (int qp = 0; qp < 2; ++qp) {
    const int qrow = q0 + w * 32 + qp * 16 + l16;
#pragma unroll
    for (int h = 0; h < 2; ++h)
      qf[qp][h] = *(const short8*)(Qh + (size_t)qrow * DK + h * 32 + quad * 8);
  }

  short8 vone;
#pragma unroll
  for (int j = 0; j < 8; ++j) vone[j] = (l16 == 0) ? (short)0x3F80 : (short)0;

  floatx4 o[2][4], ls[2];
#pragma unroll
  for (int qp = 0; qp < 2; ++qp) {
    ls[qp] = floatx4{0.f, 0.f, 0.f, 0.f};
#pragma unroll
    for (int dt = 0; dt < 4; ++dt) o[qp][dt] = floatx4{0.f, 0.f, 0.f, 0.f};
  }

  const float SC2 = 0.18033688011f;   // (1/8) * log2(e)
  const int ktmax = 2 * qtb + 2;
  short* Pw = Ps + w * 16 * AT_STR;   // this wave's 16-row P buffer

  for (int kt = 0; kt < ktmax; ++kt) {
    const int k0 = kt * 64;
    __syncthreads();
#pragma unroll
    for (int c = 0; c < 2; ++c) {
      const int row8 = w * 16 + c * 8;   // wave-uniform
      const int sw   = (c8 ^ r8) * 8;
      async_copy16(Kh + (size_t)(k0 + row8 + r8) * DK + sw, Ks + row8 * 64);
      async_copy16(Vh + (size_t)(row8 + r8) * SEQ + k0 + sw, Vs + row8 * 64);
    }
    __syncthreads();

    short8 kf[4][2], vf[4][2];
#pragma unroll
    for (int nt = 0; nt < 4; ++nt)
#pragma unroll
      for (int h = 0; h < 2; ++h) {
        kf[nt][h] = *(const short8*)(Ks + (nt * 16 + l16) * 64 + (((h * 4 + quad) ^ (l16 & 7)) * 8));
        vf[nt][h] = *(const short8*)(Vs + (nt * 16 + l16) * 64 + (((h * 4 + quad) ^ (l16 & 7)) * 8));
      }

#pragma unroll
    for (int qp = 0; qp < 2; ++qp) {
      const int frag0 = q0 + w * 32 + qp * 16;
      if (k0 <= frag0 + 15) {
        // swapped QK^T: D[key][query] -> lane holds q-row = l16,
        // keys k0 + nt*16 + quad*4 + r  (r = reg)
        floatx4 sc[4];
#pragma unroll
        for (int nt = 0; nt < 4; ++nt) {
          floatx4 z = floatx4{0.f, 0.f, 0.f, 0.f};
          z = __builtin_amdgcn_mfma_f32_16x16x32_bf16(kf[nt][0], qf[qp][0], z, 0, 0, 0);
          z = __builtin_amdgcn_mfma_f32_16x16x32_bf16(kf[nt][1], qf[qp][1], z, 0, 0, 0);
          sc[nt] = z;
        }
        const bool diag = (k0 + 63 > frag0);
        const int qrow = frag0 + l16;
#pragma unroll
        for (int nt = 0; nt < 4; ++nt)
#pragma unroll
          for (int r = 0; r < 4; ++r) {
            float s = sc[nt][r] * SC2;
            if (diag) {
              const int col = k0 + nt * 16 + quad * 4 + r;
              if (col > qrow) s = -1e30f;
            }
            sc[nt][r] = __builtin_amdgcn_exp2f(s);
          }
        // pack pairs + b64 stores: row = l16 (own q-row), cols nt*16+quad*4..+3
#pragma unroll
        for (int nt = 0; nt < 4; ++nt) {
          uint2v wv2;
          wv2[0] = cvt_pk_bf16(sc[nt][0], sc[nt][1]);
          wv2[1] = cvt_pk_bf16(sc[nt][2], sc[nt][3]);
          *(short4v*)(Pw + l16 * AT_STR + nt * 16 + quad * 4) =
              __builtin_bit_cast(short4v, wv2);
        }
        asm volatile("" ::: "memory");   // keep pf reads after P writes
        short8 pf[2];
#pragma unroll
        for (int h = 0; h < 2; ++h)
          pf[h] = *(const short8*)(Pw + l16 * AT_STR + h * 32 + quad * 8);
#pragma unroll
        for (int dt = 0; dt < 4; ++dt) {
          o[qp][dt] = __builtin_amdgcn_mfma_f32_16x16x32_bf16(pf[0], vf[dt][0], o[qp][dt], 0, 0, 0);
          o[qp][dt] = __builtin_amdgcn_mfma_f32_16x16x32_bf16(pf[1], vf[dt][1], o[qp][dt], 0, 0, 0);
        }
        ls[qp] = __builtin_amdgcn_mfma_f32_16x16x32_bf16(pf[0], vone, ls[qp], 0, 0, 0);
        ls[qp] = __builtin_amdgcn_mfma_f32_16x16x32_bf16(pf[1], vone, ls[qp], 0, 0, 0);
      }
    }
  }

  const int b = bh >> 4, h = bh & 15;
#pragma unroll
  for (int qp = 0; qp < 2; ++qp) {
    const int frag0 = q0 + w * 32 + qp * 16;
#pragma unroll
    for (int r = 0; r < 4; ++r) {
      const float lv  = __shfl(ls[qp][r], lane & 48);
      const float inv = 1.0f / fmaxf(lv, 1e-20f);
      const int row   = frag0 + quad * 4 + r;
      const size_t base = ((size_t)b * SEQ + row) * DM + h * DK;
#pragma unroll
      for (int dt = 0; dt < 4; ++dt)
        O[base + dt * 16 + l16] = f2bf(o[qp][dt][r] * inv);
    }
  }
}

// ---------------------------------------------------------------------------
// Output projection: out = O'(bf16) @ Wo_b^T + bo, fp32 out.
// 128x256 tiles (MIF=4, LDS 48 KiB), grid = 256 = one full round.
// ---------------------------------------------------------------------------
__global__ __launch_bounds__(512, 2)
void oproj256_kernel(const u16* __restrict__ A, const u16* __restrict__ Wob,
                     const float* __restrict__ bo, float* __restrict__ out)
{
  const int bx = blockIdx.x;
  const int wg = (bx & 7) * 32 + (bx >> 3);      // 256 % 8 == 0
  const int m0 = (wg >> 2) * 128, n0 = (wg & 3) * 256;

  floatx4 acc[4][4];
  gemm256_core<4>(A, Wob, m0, n0, acc);

  const int tid = threadIdx.x;
  const int wid = tid >> 6, lane = tid & 63;
  const int wm = wid >> 2, wn = wid & 3;
  const int quad = lane >> 4, l16 = lane & 15;

#pragma unroll
  for (int ni = 0; ni < 4; ++ni) {
    const int n = n0 + wn * 64 + ni * 16 + l16;
    const float bb = bo[n];
#pragma unroll
    for (int mi = 0; mi < 4; ++mi)
#pragma unroll
      for (int rr = 0; rr < 4; ++rr) {
        const int m = m0 + wm * 64 + mi * 16 + quad * 4 + rr;
        out[(size_t)m * DM + n] = acc[mi][ni][rr] + bb;
      }
  }
}

extern "C" void kernel_launch(void* const* d_in, const int* in_sizes, int n_in,
                              void* d_out, int out_size, void* d_ws, size_t ws_size,
                              hipStream_t stream)
{
  const float* x  = (const float*)d_in[0];
  const float* Wq = (const float*)d_in[1];
  const float* bq = (const float*)d_in[2];
  const float* Wk = (const float*)d_in[3];
  const float* bk = (const float*)d_in[4];
  const float* Wv = (const float*)d_in[5];
  const float* bv = (const float*)d_in[6];
  const float* Wo = (const float*)d_in[7];
  const float* bo = (const float*)d_in[8];
  float* out = (float*)d_out;

  // ws (64 MiB): Q, K, Vt, O'  (qws doubles as Wo_b after attn)
  u16* qws  = (u16*)d_ws;                       // (b,h,s,d)  bf16, 16 MiB
  u16* kws  = qws  + (size_t)M_ROWS * DM;       // (b,h,s,d)  bf16, 16 MiB
  u16* vtws = kws  + (size_t)M_ROWS * DM;       // (b,h,d,s)  bf16, 16 MiB
  u16* ows  = vtws + (size_t)M_ROWS * DM;       // O' (b,s,h*d) bf16, 16 MiB

  // d_out doubles as scratch until oproj overwrites all of it:
  //   [0, 16 MiB)  : x bf16
  //   [16, 22 MiB) : Wq/Wk/Wv bf16 packed [3][DM][DM]
  u16* xb = (u16*)d_out;
  u16* wb = xb + (size_t)M_ROWS * DM;
  u16* wo_b = qws;                              // qws dead after attn

  cvt4_kernel  <<<dim3(1024, 4), 256, 0, stream>>>(x, Wq, Wk, Wv, xb, wb);
  qkv256_kernel<<<dim3(384), 512, 0, stream>>>(xb, wb, bq, bk, bv, qws, kws, vtws);
  attn_kernel  <<<dim3(64, 16), 256, 0, stream>>>(qws, kws, vtws, ows);
  cvt1_kernel  <<<dim3(1024), 256, 0, stream>>>(Wo, wo_b, (DM * DM) / 4);
  oproj256_kernel<<<dim3(256), 512, 0, stream>>>(ows, wo_b, bo, out);
}

// Round 8
// 250.717 us; speedup vs baseline: 1.0565x; 1.0365x over previous
//
#include <hip/hip_runtime.h>
#include <hip/hip_bf16.h>

typedef __attribute__((ext_vector_type(8))) short short8;
typedef __attribute__((ext_vector_type(4))) short short4v;
typedef __attribute__((ext_vector_type(4))) float floatx4;
typedef __attribute__((ext_vector_type(2))) unsigned int uint2v;
typedef unsigned short u16;

#define B_SZ 4
#define NH   16
#define SEQ  2048
#define DM   1024
#define DK   64
#define M_ROWS (B_SZ * SEQ)   // 8192

__device__ __forceinline__ u16 f2bf(float f) {
  unsigned u = __float_as_uint(f);
  u += 0x7fff + ((u >> 16) & 1);   // RNE
  return (u16)(u >> 16);
}

// packed f32x2 -> bf16x2 (RNE), single instruction
__device__ __forceinline__ unsigned cvt_pk_bf16(float lo, float hi) {
  unsigned r;
  asm("v_cvt_pk_bf16_f32 %0, %1, %2" : "=v"(r) : "v"(lo), "v"(hi));
  return r;
}

// async global->LDS: dest = wave-uniform base + lane*16B (verified constraint)
__device__ __forceinline__ void async_copy16(const u16* g, const short* lds) {
  __builtin_amdgcn_global_load_lds(
      (const __attribute__((address_space(1))) void*)g,
      (__attribute__((address_space(3))) void*)lds,
      16, 0, 0);
}

#define BAR() do { __builtin_amdgcn_s_barrier(); asm volatile("" ::: "memory"); } while (0)

// ---------------------------------------------------------------------------
// cvt4: fp32->bf16 for x (y=0) and Wq/Wk/Wv (y=1..3). grid=(1024,4).
// ---------------------------------------------------------------------------
__global__ __launch_bounds__(256)
void cvt4_kernel(const float* __restrict__ x,
                 const float* __restrict__ wq, const float* __restrict__ wk,
                 const float* __restrict__ wv,
                 u16* __restrict__ xb, u16* __restrict__ wb)
{
  const int y = blockIdx.y;
  const float* src; u16* dst; int n4;
  if (y == 0)      { src = x;  dst = xb;                 n4 = (M_ROWS * DM) / 4; }
  else if (y == 1) { src = wq; dst = wb;                 n4 = (DM * DM) / 4; }
  else if (y == 2) { src = wk; dst = wb + DM * DM;       n4 = (DM * DM) / 4; }
  else             { src = wv; dst = wb + 2 * DM * DM;   n4 = (DM * DM) / 4; }
  for (int i = blockIdx.x * 256 + threadIdx.x; i < n4; i += gridDim.x * 256) {
    floatx4 v = ((const floatx4*)src)[i];
    short4v s;
#pragma unroll
    for (int e = 0; e < 4; ++e) s[e] = (short)f2bf(v[e]);
    ((short4v*)dst)[i] = s;
  }
}

__global__ __launch_bounds__(256)
void cvt1_kernel(const float* __restrict__ in, u16* __restrict__ out, int n4)
{
  for (int i = blockIdx.x * 256 + threadIdx.x; i < n4; i += gridDim.x * 256) {
    floatx4 v = ((const floatx4*)in)[i];
    short4v s;
#pragma unroll
    for (int e = 0; e < 4; ++e) s[e] = (short)f2bf(v[e]);
    ((short4v*)out)[i] = s;
  }
}

// ---------------------------------------------------------------------------
// GEMM core, 128x128 / BK=32 / 4 waves (wave grid 2x2, MIF=NIF=4).
// C = A(Mx1024 bf16 rm) * B^T (B Nx1024 bf16 rm), K=1024 -> 32 K-tiles,
// double-buffered.  LDS = 2 x (A 8KB + B 8KB) = 32 KiB -> with
// __launch_bounds__(256,4) (VGPR<=128) -> 4 blocks/CU co-resident.
//
// ROUND-8 rationale: round 7 (256-tile, 64KB LDS) ran at 1.5 blocks/CU --
// half the CUs carried 2 blocks (critical path ~2844 cyc/tile), half idled
// after their 1 block -> chip-avg MfmaUtil 26.6%.  4 small blocks/CU gives
// the cross-block overlap that fills barrier/LDS-queue stalls (m97/m114
// mechanism), and grid 1536/512 makes the load fine-grained (tail <= 1/6).
// Keeps round 7's verified components: counted vmcnt, 2-barrier ledger,
// LDS XOR swizzle, V^T-contiguous epilogue.
//
// Swizzle (64B rows, 16B units): LDS[r][u] = G[r][u ^ (r&3) ^ ((r>>2)&3)].
// Stage side: wave w, instr j covers rows oct*16 + (lane>>2), oct = w*2+j;
//   dst linear (global_load_lds: base + lane*16B);
//   src unit cu = (lane&3) ^ ((lane>>2)&3) ^ ((lane>>4)&3)
//   [row&3 = (lane>>2)&3 and (row>>2)&3 = (lane>>4)&3 since oct*16 is a
//    multiple of 16 -> same involution as the measured round-7 layout].
// Read side: frag row R = 16k + l16 -> unit = quad ^ (l16&3) ^ ((l16>>2)&3).
//
// 2-barrier ledger per tile t (buf c = t&1):  issue all 8 ds_reads (A4+B4);
// MFMA q1(m-lo,n-lo) q2(m-lo,n-hi) q3(m-hi,n-hi) [compiler's counted lgkm
// waits cover the reads]; BAR(a) [all waves' reads of buf c retired];
// stage tile t+2 -> buf c (4 gloads); vmcnt(4) [outstanding after issue =
// t+1's 4 + t+2's 4 = 8; retires t+1's -> landed]; q4(m-hi,n-lo) from regs;
// BAR(b) [every wave's t+1 loads landed].  Last 2 tiles: vmcnt(0) drain.
// ---------------------------------------------------------------------------
__device__ __forceinline__ void stage_tile128(
    const u16* __restrict__ Asrc, const u16* __restrict__ Bsrc,  // (row0, k0)
    short* sA, short* sB, int w, int lane)
{
  const int cu  = (lane & 3) ^ ((lane >> 2) & 3) ^ ((lane >> 4) & 3);
  const int rlo = lane >> 2;                      // 0..15
#pragma unroll
  for (int j = 0; j < 2; ++j) {
    const int oct = w * 2 + j;                    // 0..7 (16 rows each)
    const int row = oct * 16 + rlo;
    async_copy16(Asrc + (size_t)row * DM + cu * 8, sA + oct * 512);
  }
#pragma unroll
  for (int j = 0; j < 2; ++j) {
    const int oct = w * 2 + j;
    const int row = oct * 16 + rlo;
    async_copy16(Bsrc + (size_t)row * DM + cu * 8, sB + oct * 512);
  }
}

__device__ __forceinline__ void gemm128_core(
    const u16* __restrict__ A, const u16* __restrict__ B,
    int m0, int n0, floatx4 (&acc)[4][4])
{
  __shared__ short smem[16384];                   // 32 KiB: 2 x (A 4096 + B 4096)

  const int tid  = threadIdx.x;
  const int w    = tid >> 6;
  const int lane = tid & 63;
  const int wm   = w >> 1, wn = w & 1;            // wave grid 2(M) x 2(N)
  const int quad = lane >> 4, l16 = lane & 15;
  const int rswz = (l16 & 3) ^ ((l16 >> 2) & 3);

  short* sA_[2] = { smem,        smem + 8192 };
  short* sB_[2] = { smem + 4096, smem + 12288 };

#pragma unroll
  for (int mi = 0; mi < 4; ++mi)
#pragma unroll
    for (int ni = 0; ni < 4; ++ni)
      acc[mi][ni] = floatx4{0.f, 0.f, 0.f, 0.f};

  const u16* Abase = A + (size_t)m0 * DM;
  const u16* Bbase = B + (size_t)n0 * DM;

  // ---- prologue: stage tiles 0 (buf0) and 1 (buf1), 4 loads/wave each ----
  stage_tile128(Abase,      Bbase,      sA_[0], sB_[0], w, lane);
  stage_tile128(Abase + 32, Bbase + 32, sA_[1], sB_[1], w, lane);
  asm volatile("s_waitcnt vmcnt(4)" ::: "memory");   // tile0 landed
  BAR();

  short8 af[4], bf[4];

  for (int i = 0; i < 16; ++i) {                  // tiles 2i, 2i+1
    const bool nl = (i < 15);                     // stage tiles 2i+2 / 2i+3
#pragma unroll
    for (int half = 0; half < 2; ++half) {
      short* cA = sA_[half];
      short* cB = sB_[half];
      const int kof_n = (2 * i + 2 + half) * 32;  // staging k-offset (if nl)

      // ---- issue ALL 8 K-tile ds_reads (B-lo, A, B-hi) ----
#pragma unroll
      for (int nt = 0; nt < 2; ++nt)
        bf[nt] = *(const short8*)(cB + (wn * 64 + nt * 16 + l16) * 32
                                     + ((quad ^ rswz) << 3));
#pragma unroll
      for (int mi = 0; mi < 4; ++mi)
        af[mi] = *(const short8*)(cA + (wm * 64 + mi * 16 + l16) * 32
                                     + ((quad ^ rswz) << 3));
#pragma unroll
      for (int nt = 2; nt < 4; ++nt)
        bf[nt] = *(const short8*)(cB + (wn * 64 + nt * 16 + l16) * 32
                                     + ((quad ^ rswz) << 3));

      // ---- q1 (m-lo x n-lo), q2 (m-lo x n-hi), q3 (m-hi x n-hi) ----
      __builtin_amdgcn_s_setprio(1);
#pragma unroll
      for (int mi = 0; mi < 2; ++mi)
#pragma unroll
        for (int nt = 0; nt < 4; ++nt)
          acc[mi][nt] = __builtin_amdgcn_mfma_f32_16x16x32_bf16(
              af[mi], bf[nt], acc[mi][nt], 0, 0, 0);
#pragma unroll
      for (int mi = 2; mi < 4; ++mi)
#pragma unroll
        for (int nt = 2; nt < 4; ++nt)
          acc[mi][nt] = __builtin_amdgcn_mfma_f32_16x16x32_bf16(
              af[mi], bf[nt], acc[mi][nt], 0, 0, 0);
      __builtin_amdgcn_s_setprio(0);

      BAR();   // hazard (a): all waves' reads of this buffer retired

      if (nl) {
        stage_tile128(Abase + kof_n, Bbase + kof_n, cA, cB, w, lane);
        asm volatile("s_waitcnt vmcnt(4)" ::: "memory");  // tile t+1 landed
      } else {
        asm volatile("s_waitcnt vmcnt(0)" ::: "memory");  // drain final tiles
      }

      // ---- q4 (m-hi x n-lo): pure reg ops, overlaps staging issue ----
      __builtin_amdgcn_s_setprio(1);
#pragma unroll
      for (int mi = 2; mi < 4; ++mi)
#pragma unroll
        for (int nt = 0; nt < 2; ++nt)
          acc[mi][nt] = __builtin_amdgcn_mfma_f32_16x16x32_bf16(
              af[mi], bf[nt], acc[mi][nt], 0, 0, 0);
      __builtin_amdgcn_s_setprio(0);

      BAR();   // hazard (b): ALL waves' t+1 loads landed
    }
  }
}

// ---------------------------------------------------------------------------
// Fused QKV projection, 128^2 tiles, 256 threads. grid = (1536):
// [0,512) Q, [512,1024) K, [1024,1536) V^T (operands swapped:
// C[e][s] = sum_d Wv[e][d] x[s][d] -> (b,h,d,s) store contiguous in s).
// ---------------------------------------------------------------------------
__global__ __launch_bounds__(256, 4)
void qkv128_kernel(const u16* __restrict__ xb, const u16* __restrict__ wb,
                   const float* __restrict__ bq, const float* __restrict__ bk,
                   const float* __restrict__ bv,
                   u16* __restrict__ Qo, u16* __restrict__ Ko, u16* __restrict__ Vto)
{
  const int bx = blockIdx.x;
  const int wg = (bx & 7) * 192 + (bx >> 3);     // bijective XCD swizzle (1536%8==0)
  const int mat = wg >> 9;
  const int r   = wg & 511;

  int m0, n0;
  const u16 *A, *Bm;
  if (mat < 2) { m0 = (r >> 3) * 128; n0 = (r & 7) * 128; A = xb; Bm = wb + (size_t)mat * DM * DM; }
  else         { m0 = (r & 7) * 128;  n0 = (r >> 3) * 128; A = wb + (size_t)2 * DM * DM; Bm = xb; }

  floatx4 acc[4][4];
  gemm128_core(A, Bm, m0, n0, acc);

  const int tid = threadIdx.x;
  const int w = tid >> 6, lane = tid & 63;
  const int wm = w >> 1, wn = w & 1;
  const int quad = lane >> 4, l16 = lane & 15;

  if (mat < 2) {
    u16* dst = (mat == 0) ? Qo : Ko;
    const float* bias = (mat == 0) ? bq : bk;
#pragma unroll
    for (int ni = 0; ni < 4; ++ni) {
      const int n = n0 + wn * 64 + ni * 16 + l16;
      const float bb = bias[n];
      const int h = n >> 6, d = n & 63;
#pragma unroll
      for (int mi = 0; mi < 4; ++mi)
#pragma unroll
        for (int rr = 0; rr < 4; ++rr) {
          const int m = m0 + wm * 64 + mi * 16 + quad * 4 + rr;
          const int b = m >> 11, s = m & 2047;
          dst[((size_t)(b * NH + h) * SEQ + s) * DK + d] = f2bf(acc[mi][ni][rr] + bb);
        }
    }
  } else {
#pragma unroll
    for (int mi = 0; mi < 4; ++mi)
#pragma unroll
      for (int rr = 0; rr < 4; ++rr) {
        const int m = m0 + wm * 64 + mi * 16 + quad * 4 + rr;    // e in [0,1024)
        const float bb = bv[m];
        const int h = m >> 6, d = m & 63;
#pragma unroll
        for (int ni = 0; ni < 4; ++ni) {
          const int n = n0 + wn * 64 + ni * 16 + l16;            // (b,s) in [0,8192)
          const int b = n >> 11, s = n & 2047;
          Vto[((size_t)(b * NH + h) * DK + d) * SEQ + s] = f2bf(acc[mi][ni][rr] + bb);
        }
      }
  }
}

// ---------------------------------------------------------------------------
// Flash attention, causal, exp2-domain, no-rescale online softmax.
// grid = (64 bh, 16 qt-reversed). Block = 128 q-rows, 4 waves x 32 rows.
// Swapped QK^T (lane-local P) + cvt_pk + b64 P-stores (round 4, passed).
// ---------------------------------------------------------------------------
#define AT_STR 72
__global__ __launch_bounds__(256, 2)
void attn_kernel(const u16* __restrict__ Q, const u16* __restrict__ Kx,
                 const u16* __restrict__ Vt, u16* __restrict__ O)
{
  __shared__ short Ks[64 * 64];
  __shared__ short Vs[64 * 64];
  __shared__ __align__(16) short Ps[4 * 16 * AT_STR];   // 16 rows per wave

  const int bh  = blockIdx.x;
  const int qtb = 15 - (int)blockIdx.y;
  const int q0  = qtb * 128;
  const int tid = threadIdx.x;
  const int w = tid >> 6, lane = tid & 63;
  const int quad = lane >> 4, l16 = lane & 15;
  const int r8 = lane >> 3, c8 = lane & 7;

  const u16* Qh = Q  + (size_t)bh * SEQ * DK;
  const u16* Kh = Kx + (size_t)bh * SEQ * DK;
  const u16* Vh = Vt + (size_t)bh * DK * SEQ;

  short8 qf[2][2];
#pragma unroll
  for (int qp = 0; qp < 2; ++qp) {
    const int qrow = q0 + w * 32 + qp * 16 + l16;
#pragma unroll
    for (int h = 0; h < 2; ++h)
      qf[qp][h] = *(const short8*)(Qh + (size_t)qrow * DK + h * 32 + quad * 8);
  }

  short8 vone;
#pragma unroll
  for (int j = 0; j < 8; ++j) vone[j] = (l16 == 0) ? (short)0x3F80 : (short)0;

  floatx4 o[2][4], ls[2];
#pragma unroll
  for (int qp = 0; qp < 2; ++qp) {
    ls[qp] = floatx4{0.f, 0.f, 0.f, 0.f};
#pragma unroll
    for (int dt = 0; dt < 4; ++dt) o[qp][dt] = floatx4{0.f, 0.f, 0.f, 0.f};
  }

  const float SC2 = 0.18033688011f;   // (1/8) * log2(e)
  const int ktmax = 2 * qtb + 2;
  short* Pw = Ps + w * 16 * AT_STR;   // this wave's 16-row P buffer

  for (int kt = 0; kt < ktmax; ++kt) {
    const int k0 = kt * 64;
    __syncthreads();
#pragma unroll
    for (int c = 0; c < 2; ++c) {
      const int row8 = w * 16 + c * 8;   // wave-uniform
      const int sw   = (c8 ^ r8) * 8;
      async_copy16(Kh + (size_t)(k0 + row8 + r8) * DK + sw, Ks + row8 * 64);
      async_copy16(Vh + (size_t)(row8 + r8) * SEQ + k0 + sw, Vs + row8 * 64);
    }
    __syncthreads();

    short8 kf[4][2], vf[4][2];
#pragma unroll
    for (int nt = 0; nt < 4; ++nt)
#pragma unroll
      for (int h = 0; h < 2; ++h) {
        kf[nt][h] = *(const short8*)(Ks + (nt * 16 + l16) * 64 + (((h * 4 + quad) ^ (l16 & 7)) * 8));
        vf[nt][h] = *(const short8*)(Vs + (nt * 16 + l16) * 64 + (((h * 4 + quad) ^ (l16 & 7)) * 8));
      }

#pragma unroll
    for (int qp = 0; qp < 2; ++qp) {
      const int frag0 = q0 + w * 32 + qp * 16;
      if (k0 <= frag0 + 15) {
        // swapped QK^T: D[key][query] -> lane holds q-row = l16,
        // keys k0 + nt*16 + quad*4 + r  (r = reg)
        floatx4 sc[4];
#pragma unroll
        for (int nt = 0; nt < 4; ++nt) {
          floatx4 z = floatx4{0.f, 0.f, 0.f, 0.f};
          z = __builtin_amdgcn_mfma_f32_16x16x32_bf16(kf[nt][0], qf[qp][0], z, 0, 0, 0);
          z = __builtin_amdgcn_mfma_f32_16x16x32_bf16(kf[nt][1], qf[qp][1], z, 0, 0, 0);
          sc[nt] = z;
        }
        const bool diag = (k0 + 63 > frag0);
        const int qrow = frag0 + l16;
#pragma unroll
        for (int nt = 0; nt < 4; ++nt)
#pragma unroll
          for (int r = 0; r < 4; ++r) {
            float s = sc[nt][r] * SC2;
            if (diag) {
              const int col = k0 + nt * 16 + quad * 4 + r;
              if (col > qrow) s = -1e30f;
            }
            sc[nt][r] = __builtin_amdgcn_exp2f(s);
          }
        // pack pairs + b64 stores: row = l16 (own q-row), cols nt*16+quad*4..+3
#pragma unroll
        for (int nt = 0; nt < 4; ++nt) {
          uint2v wv2;
          wv2[0] = cvt_pk_bf16(sc[nt][0], sc[nt][1]);
          wv2[1] = cvt_pk_bf16(sc[nt][2], sc[nt][3]);
          *(short4v*)(Pw + l16 * AT_STR + nt * 16 + quad * 4) =
              __builtin_bit_cast(short4v, wv2);
        }
        asm volatile("" ::: "memory");   // keep pf reads after P writes
        short8 pf[2];
#pragma unroll
        for (int h = 0; h < 2; ++h)
          pf[h] = *(const short8*)(Pw + l16 * AT_STR + h * 32 + quad * 8);
#pragma unroll
        for (int dt = 0; dt < 4; ++dt) {
          o[qp][dt] = __builtin_amdgcn_mfma_f32_16x16x32_bf16(pf[0], vf[dt][0], o[qp][dt], 0, 0, 0);
          o[qp][dt] = __builtin_amdgcn_mfma_f32_16x16x32_bf16(pf[1], vf[dt][1], o[qp][dt], 0, 0, 0);
        }
        ls[qp] = __builtin_amdgcn_mfma_f32_16x16x32_bf16(pf[0], vone, ls[qp], 0, 0, 0);
        ls[qp] = __builtin_amdgcn_mfma_f32_16x16x32_bf16(pf[1], vone, ls[qp], 0, 0, 0);
      }
    }
  }

  const int b = bh >> 4, h = bh & 15;
#pragma unroll
  for (int qp = 0; qp < 2; ++qp) {
    const int frag0 = q0 + w * 32 + qp * 16;
#pragma unroll
    for (int r = 0; r < 4; ++r) {
      const float lv  = __shfl(ls[qp][r], lane & 48);
      const float inv = 1.0f / fmaxf(lv, 1e-20f);
      const int row   = frag0 + quad * 4 + r;
      const size_t base = ((size_t)b * SEQ + row) * DM + h * DK;
#pragma unroll
      for (int dt = 0; dt < 4; ++dt)
        O[base + dt * 16 + l16] = f2bf(o[qp][dt][r] * inv);
    }
  }
}

// ---------------------------------------------------------------------------
// Output projection: out = O'(bf16) @ Wo_b^T + bo, fp32 out.
// 128^2 tiles, grid = 512 -> 2 balanced rounds at 4 blocks/CU.
// ---------------------------------------------------------------------------
__global__ __launch_bounds__(256, 4)
void oproj128_kernel(const u16* __restrict__ A, const u16* __restrict__ Wob,
                     const float* __restrict__ bo, float* __restrict__ out)
{
  const int bx = blockIdx.x;
  const int wg = (bx & 7) * 64 + (bx >> 3);      // 512 % 8 == 0
  const int m0 = (wg >> 3) * 128, n0 = (wg & 7) * 128;

  floatx4 acc[4][4];
  gemm128_core(A, Wob, m0, n0, acc);

  const int tid = threadIdx.x;
  const int w = tid >> 6, lane = tid & 63;
  const int wm = w >> 1, wn = w & 1;
  const int quad = lane >> 4, l16 = lane & 15;

#pragma unroll
  for (int ni = 0; ni < 4; ++ni) {
    const int n = n0 + wn * 64 + ni * 16 + l16;
    const float bb = bo[n];
#pragma unroll
    for (int mi = 0; mi < 4; ++mi)
#pragma unroll
      for (int rr = 0; rr < 4; ++rr) {
        const int m = m0 + wm * 64 + mi * 16 + quad * 4 + rr;
        out[(size_t)m * DM + n] = acc[mi][ni][rr] + bb;
      }
  }
}

extern "C" void kernel_launch(void* const* d_in, const int* in_sizes, int n_in,
                              void* d_out, int out_size, void* d_ws, size_t ws_size,
                              hipStream_t stream)
{
  const float* x  = (const float*)d_in[0];
  const float* Wq = (const float*)d_in[1];
  const float* bq = (const float*)d_in[2];
  const float* Wk = (const float*)d_in[3];
  const float* bk = (const float*)d_in[4];
  const float* Wv = (const float*)d_in[5];
  const float* bv = (const float*)d_in[6];
  const float* Wo = (const float*)d_in[7];
  const float* bo = (const float*)d_in[8];
  float* out = (float*)d_out;

  // ws (64 MiB): Q, K, Vt, O'  (qws doubles as Wo_b after attn)
  u16* qws  = (u16*)d_ws;                       // (b,h,s,d)  bf16, 16 MiB
  u16* kws  = qws  + (size_t)M_ROWS * DM;       // (b,h,s,d)  bf16, 16 MiB
  u16* vtws = kws  + (size_t)M_ROWS * DM;       // (b,h,d,s)  bf16, 16 MiB
  u16* ows  = vtws + (size_t)M_ROWS * DM;       // O' (b,s,h*d) bf16, 16 MiB

  // d_out doubles as scratch until oproj overwrites all of it:
  //   [0, 16 MiB)  : x bf16
  //   [16, 22 MiB) : Wq/Wk/Wv bf16 packed [3][DM][DM]
  u16* xb = (u16*)d_out;
  u16* wb = xb + (size_t)M_ROWS * DM;
  u16* wo_b = qws;                              // qws dead after attn

  cvt4_kernel  <<<dim3(1024, 4), 256, 0, stream>>>(x, Wq, Wk, Wv, xb, wb);
  qkv128_kernel<<<dim3(1536), 256, 0, stream>>>(xb, wb, bq, bk, bv, qws, kws, vtws);
  attn_kernel  <<<dim3(64, 16), 256, 0, stream>>>(qws, kws, vtws, ows);
  cvt1_kernel  <<<dim3(1024), 256, 0, stream>>>(Wo, wo_b, (DM * DM) / 4);
  oproj128_kernel<<<dim3(512), 256, 0, stream>>>(ows, wo_b, bo, out);
}